// Round 6
// baseline (1185.776 us; speedup 1.0000x reference)
//
#include <hip/hip_runtime.h>
#include <cstdint>

#define N_NODESC 50000
#define N_EDGESC 500000
#define E_TOT    550000
#define DIM      144
#define NGRAPH   64
#define EPSV     1e-5f
#define SCAN_NB  ((N_NODESC + 511)/512)   // 98 blocks of 512 elements

__device__ __forceinline__ float lrelu(float x){ return x > 0.f ? x : 0.2f*x; }

// bf16 round-to-nearest-even pack/unpack
__device__ __forceinline__ unsigned short f2bf(float f){
  unsigned u = __float_as_uint(f);
  u += 0x7FFF + ((u >> 16) & 1);
  return (unsigned short)(u >> 16);
}
__device__ __forceinline__ float bf2f(unsigned short b){
  return __uint_as_float(((unsigned)b) << 16);
}

// ---------------- CSR build (by dst, self-loops appended) ----------------
__global__ void k_count(const int* __restrict__ ei, int* __restrict__ deg){
  int e = blockIdx.x*blockDim.x + threadIdx.x;
  if (e >= E_TOT) return;
  int d = (e < N_EDGESC) ? ei[N_EDGESC + e] : (e - N_EDGESC);
  atomicAdd(&deg[d], 1);
}

__global__ __launch_bounds__(256) void k_scan1(const int* __restrict__ deg,
    int* __restrict__ scanned, int* __restrict__ bsum){
  __shared__ int ls[256];
  int b = blockIdx.x, t = threadIdx.x;
  int i0 = b*512 + 2*t;
  int e0 = (i0   < N_NODESC) ? deg[i0]   : 0;
  int e1 = (i0+1 < N_NODESC) ? deg[i0+1] : 0;
  int s = e0 + e1;
  ls[t] = s;
  __syncthreads();
  #pragma unroll
  for (int ofs=1; ofs<256; ofs<<=1){
    int v = (t >= ofs) ? ls[t-ofs] : 0;
    __syncthreads();
    ls[t] += v;
    __syncthreads();
  }
  int excl = ls[t] - s;
  if (i0   < N_NODESC) scanned[i0]   = excl;
  if (i0+1 < N_NODESC) scanned[i0+1] = excl + e0;
  if (t == 255) bsum[b] = ls[255];
}

__global__ void k_scan2(int* __restrict__ bsum){
  __shared__ int ls[128];
  int t = threadIdx.x;
  int v = (t < SCAN_NB) ? bsum[t] : 0;
  ls[t] = v;
  __syncthreads();
  #pragma unroll
  for (int ofs=1; ofs<128; ofs<<=1){
    int u = (t >= ofs) ? ls[t-ofs] : 0;
    __syncthreads();
    ls[t] += u;
    __syncthreads();
  }
  if (t < SCAN_NB) bsum[t] = ls[t] - v;
}

__global__ __launch_bounds__(256) void k_scan3(const int* __restrict__ scanned,
    const int* __restrict__ bsum, int* __restrict__ row_ptr, int* __restrict__ cursor){
  int i = blockIdx.x*blockDim.x + threadIdx.x;
  if (i < N_NODESC){
    int v = scanned[i] + bsum[i >> 9];
    row_ptr[i] = v; cursor[i] = v;
  }
  if (i == 0) row_ptr[N_NODESC] = E_TOT;
}

__global__ void k_scatter(const int* __restrict__ ei, int* __restrict__ cursor,
                          int* __restrict__ col){
  int e = blockIdx.x*blockDim.x + threadIdx.x;
  if (e >= E_TOT) return;
  int s, d;
  if (e < N_EDGESC){ s = ei[e]; d = ei[N_EDGESC + e]; } else { s = e - N_EDGESC; d = s; }
  int pos = atomicAdd(&cursor[d], 1);
  col[pos] = s;
}

// ---------------- fused GEMM + BN-on-input + attention logits ----------------
#define KC 36
#define SW_STRIDE 192   // 16 groups * 12
#define SAT_STRIDE 68
__global__ __launch_bounds__(256) void k_gemm_fused(
    const float* __restrict__ A, const float* __restrict__ W,
    const float* __restrict__ bias,
    const float* __restrict__ a_s, const float* __restrict__ a_d,
    float* __restrict__ outf, unsigned short* __restrict__ outb,
    float* __restrict__ al_s, float* __restrict__ al_d,
    int K, int H,
    const float* __restrict__ bnsum, const float* __restrict__ bngam,
    const float* __restrict__ bnbet){
  extern __shared__ float smem[];
  float* sW  = smem;                 // KC * 192
  float* sAT = smem + KC*SW_STRIDE;  // KC * 68
  float* sBN = sAT + KC*SAT_STRIDE;  // 2*144 (scale, shift)
  int t = threadIdx.x;
  int m0 = blockIdx.x * 64;
  int rg = t & 15, cg = t >> 4;
  int c0 = cg * 9;

  if (bnsum){
    for (int i=t; i<K; i+=256){
      float mu  = bnsum[i] * (1.f/N_NODESC);
      float var = bnsum[K+i] * (1.f/N_NODESC) - mu*mu;
      float inv = rsqrtf(var + EPSV);
      float sc = inv * bngam[i];
      sBN[i] = sc; sBN[K+i] = bnbet[i] - mu*sc;
    }
    __syncthreads();
  }

  float acc[4][9];
  #pragma unroll
  for (int i=0;i<4;++i)
    #pragma unroll
    for (int j=0;j<9;++j) acc[i][j] = bias ? bias[c0+j] : 0.f;

  for (int k0 = 0; k0 < K; k0 += KC){
    int kc = min(KC, K - k0);
    __syncthreads();
    for (int i = t; i < kc*144; i += 256){
      int kk = i / 144, c = i - kk*144;
      int g = c / 9, j = c - g*9;
      sW[kk*SW_STRIDE + g*12 + j] = W[(size_t)(k0+kk)*144 + c];
    }
    for (int i = t; i < 64*kc; i += 256){
      int r = i / kc, kk = i - r*kc;
      int m = m0 + r; if (m >= N_NODESC) m = N_NODESC - 1;
      float v = A[(size_t)m*K + k0 + kk];
      if (bnsum) v = fmaf(v, sBN[k0+kk], sBN[K+k0+kk]);
      sAT[kk*SAT_STRIDE + r] = v;
    }
    __syncthreads();
    for (int k = 0; k < kc; ++k){
      float4 a4 = *(const float4*)&sAT[k*SAT_STRIDE + rg*4];
      const float* wp = &sW[k*SW_STRIDE + cg*12];
      float4 w0 = *(const float4*)(wp);
      float4 w1 = *(const float4*)(wp+4);
      float  w8 = wp[8];
      float av[4] = {a4.x, a4.y, a4.z, a4.w};
      float wv[9] = {w0.x,w0.y,w0.z,w0.w,w1.x,w1.y,w1.z,w1.w,w8};
      #pragma unroll
      for (int i=0;i<4;++i)
        #pragma unroll
        for (int j=0;j<9;++j) acc[i][j] = fmaf(av[i], wv[j], acc[i][j]);
    }
  }

  if (H > 0){
    __syncthreads();
    float* sRs = smem;
    float* sRd = smem + 64*17;
    float ps[4], pd[4];
    #pragma unroll
    for (int i=0;i<4;++i){ ps[i]=0.f; pd[i]=0.f; }
    #pragma unroll
    for (int j=0;j<9;++j){
      float asj = a_s[c0+j], adj = a_d[c0+j];
      #pragma unroll
      for (int i=0;i<4;++i){ ps[i] = fmaf(acc[i][j], asj, ps[i]); pd[i] = fmaf(acc[i][j], adj, pd[i]); }
    }
    #pragma unroll
    for (int i=0;i<4;++i){
      sRs[(rg*4+i)*17 + cg] = ps[i];
      sRd[(rg*4+i)*17 + cg] = pd[i];
    }
    __syncthreads();
    int G = 16 / H;
    for (int idx = t; idx < 64*H; idx += 256){
      int r = idx / H, h = idx - r*H;
      float ss = 0.f, sd = 0.f;
      for (int g2 = h*G; g2 < (h+1)*G; ++g2){ ss += sRs[r*17+g2]; sd += sRd[r*17+g2]; }
      int m = m0 + r;
      if (m < N_NODESC){ al_s[m*H+h] = ss; al_d[m*H+h] = sd; }
    }
  }

  #pragma unroll
  for (int i=0;i<4;++i){
    int m = m0 + rg*4 + i;
    if (m < N_NODESC){
      if (outb){
        unsigned short* o = outb + (size_t)m*DIM + c0;
        #pragma unroll
        for (int j=0;j<9;++j) o[j] = f2bf(acc[i][j]);
      } else {
        float* o = outf + (size_t)m*DIM + c0;
        #pragma unroll
        for (int j=0;j<9;++j) o[j] = acc[i][j];
      }
    }
  }
}

// ---------------- segment softmax: one thread per (node, head) ----------------
// Writes normalized attention weights w = exp(sc - m)/den in-place into esc[E*H].
__global__ __launch_bounds__(256) void k_edge_softmax(
    const float* __restrict__ al_s, const float* __restrict__ al_d,
    const int* __restrict__ row_ptr, const int* __restrict__ col,
    float* __restrict__ esc, int H){
  int idx = blockIdx.x*blockDim.x + threadIdx.x;
  if (idx >= N_NODESC*H) return;
  int n = idx / H, h = idx - n*H;
  int p0 = row_ptr[n], p1 = row_ptr[n+1];
  float ald = al_d[idx];
  float m = -3.4e38f;
  for (int e = p0; e < p1; ++e){
    float sc = lrelu(al_s[col[e]*H + h] + ald);
    esc[(size_t)e*H + h] = sc;
    m = fmaxf(m, sc);
  }
  float den = 0.f;
  for (int e = p0; e < p1; ++e) den += __expf(esc[(size_t)e*H + h] - m);
  float inv = 1.f/(den + 1e-16f);
  for (int e = p0; e < p1; ++e)
    esc[(size_t)e*H + h] = __expf(esc[(size_t)e*H + h] - m) * inv;
}

// ---------------- weighted gather: one thread per (node, channel-pair) ----------------
// hp is bf16 read as uint (2 channels/lane). No LDS, no barriers. +bias+ReLU.
__global__ __launch_bounds__(256) void k_aggregate2(
    const unsigned* __restrict__ hp2, const float* __restrict__ w,
    const int* __restrict__ row_ptr, const int* __restrict__ col,
    const float* __restrict__ bias, float* __restrict__ out,
    int H, int C2){             // C2 = C/2 (9 for 8-head, 72 for 1-head)
  int idx = blockIdx.x*blockDim.x + threadIdx.x;
  if (idx >= N_NODESC*72) return;
  int n = idx / 72, cp = idx - n*72;
  int h = cp / C2;
  int p0 = row_ptr[n], p1 = row_ptr[n+1];
  float a0 = 0.f, a1 = 0.f;
  for (int e = p0; e < p1; ++e){
    int s = col[e];
    float wgt = w[(size_t)e*H + h];
    unsigned v = hp2[(size_t)s*72 + cp];
    a0 = fmaf(wgt, __uint_as_float(v << 16), a0);
    a1 = fmaf(wgt, __uint_as_float(v & 0xFFFF0000u), a1);
  }
  int c0 = 2*cp;
  float2 r;
  r.x = fmaxf(a0 + bias[c0],   0.f);
  r.y = fmaxf(a1 + bias[c0+1], 0.f);
  *(float2*)&out[(size_t)n*DIM + c0] = r;
}

// ---------------- batchnorm stats: register accumulate, coalesced ----------------
__global__ __launch_bounds__(192) void k_bnstats(const float* __restrict__ h,
                                                 float* __restrict__ sums){
  int t = threadIdx.x;
  if (t >= DIM) return;
  int rows = (N_NODESC + gridDim.x - 1)/gridDim.x;
  int n0 = blockIdx.x*rows, n1 = min(N_NODESC, n0+rows);
  float s = 0.f, q = 0.f;
  for (int n = n0; n < n1; ++n){
    float v = h[(size_t)n*DIM + t];
    s += v; q += v*v;
  }
  atomicAdd(&sums[t], s);
  atomicAdd(&sums[DIM+t], q);
}

// ---------------- per-graph mean pool (batch is sorted) ----------------
__device__ int lbound(const int* a, int n, int v){
  int lo = 0, hi = n;
  while (lo < hi){ int m = (lo+hi) >> 1; if (a[m] < v) lo = m+1; else hi = m; }
  return lo;
}

__global__ __launch_bounds__(192) void k_pool(const float* __restrict__ h,
    const int* __restrict__ batch, float* __restrict__ sums, int* __restrict__ cnts){
  int g = blockIdx.x & 63, part = blockIdx.x >> 6;     // 8 parts per graph
  __shared__ int sb[2];
  if (threadIdx.x == 0){ sb[0] = lbound(batch, N_NODESC, g); sb[1] = lbound(batch, N_NODESC, g+1); }
  __syncthreads();
  int lo = sb[0], hi = sb[1];
  int t = threadIdx.x;
  if (t < DIM){
    float acc = 0.f;
    for (int n = lo + part; n < hi; n += 8) acc += h[(size_t)n*DIM + t];
    atomicAdd(&sums[g*DIM + t], acc);
  }
  if (t == 0 && part == 0) cnts[g] = hi - lo;
}

// ---------------- MLP head (final BN fused into pooled-mean load) ----------------
__global__ __launch_bounds__(256) void k_mlp(const float* __restrict__ sums,
    const int* __restrict__ cnts,
    const float* __restrict__ bn3, const float* __restrict__ gam3,
    const float* __restrict__ bet3,
    const float* __restrict__ M1, const float* __restrict__ bm1,
    const float* __restrict__ gm1, const float* __restrict__ bb1,
    const float* __restrict__ M2, const float* __restrict__ bm2,
    const float* __restrict__ gm2, const float* __restrict__ bb2,
    const float* __restrict__ M3, const float* __restrict__ bm3,
    float* __restrict__ out){
  __shared__ float sg[64*144];
  __shared__ float s1[64*72];
  __shared__ float s2[64*36];
  __shared__ float stat[144];
  int t = threadIdx.x;
  for (int i=t; i<64*144; i+=256){
    int g=i/144, c=i-g*144;
    float cf=(float)max(cnts[g],1);
    float mu  = bn3[c]*(1.f/N_NODESC);
    float var = bn3[144+c]*(1.f/N_NODESC) - mu*mu;
    float inv = rsqrtf(var + EPSV);
    float sc = inv*gam3[c];
    sg[i] = (sums[i]/cf - mu)*sc + bet3[c];
  }
  __syncthreads();
  for (int i=t; i<64*72; i+=256){
    int r=i/72, c=i-r*72; float a=bm1[c];
    for (int k=0;k<144;++k) a = fmaf(sg[r*144+k], M1[k*72+c], a);
    s1[i]=a;
  }
  __syncthreads();
  if (t < 72){
    float s=0.f,q=0.f;
    for (int r=0;r<64;++r){ float v=s1[r*72+t]; s+=v; q+=v*v; }
    float mu=s*(1.f/64.f); float var=q*(1.f/64.f)-mu*mu;
    stat[t]=mu; stat[72+t]=rsqrtf(var+EPSV);
  }
  __syncthreads();
  for (int i=t; i<64*72; i+=256){
    int c=i%72; float v=fmaf((s1[i]-stat[c])*stat[72+c], gm1[c], bb1[c]); s1[i]=fmaxf(v,0.f);
  }
  __syncthreads();
  for (int i=t; i<64*36; i+=256){
    int r=i/36, c=i-r*36; float a=bm2[c];
    for (int k=0;k<72;++k) a = fmaf(s1[r*72+k], M2[k*36+c], a);
    s2[i]=a;
  }
  __syncthreads();
  if (t < 36){
    float s=0.f,q=0.f;
    for (int r=0;r<64;++r){ float v=s2[r*36+t]; s+=v; q+=v*v; }
    float mu=s*(1.f/64.f); float var=q*(1.f/64.f)-mu*mu;
    stat[t]=mu; stat[36+t]=rsqrtf(var+EPSV);
  }
  __syncthreads();
  for (int i=t; i<64*36; i+=256){
    int c=i%36; float v=fmaf((s2[i]-stat[c])*stat[36+c], gm2[c], bb2[c]); s2[i]=fmaxf(v,0.f);
  }
  __syncthreads();
  for (int i=t; i<64*112; i+=256){
    int r=i/112, c=i-r*112; float a=bm3[c];
    for (int k=0;k<36;++k) a = fmaf(s2[r*36+k], M3[k*112+c], a);
    out[i]=a;
  }
}

extern "C" void kernel_launch(void* const* d_in, const int* in_sizes, int n_in,
                              void* d_out, int out_size, void* d_ws, size_t ws_size,
                              hipStream_t stream){
  const float* x    = (const float*)d_in[0];
  const int*   ei   = (const int*)d_in[1];
  const int*   batch= (const int*)d_in[2];
  const float* We   = (const float*)d_in[3];
  const float* be   = (const float*)d_in[4];
  const float* Wg   = (const float*)d_in[5];
  const float* a_sg = (const float*)d_in[6];
  const float* a_dg = (const float*)d_in[7];
  const float* bg   = (const float*)d_in[8];
  const float* gam  = (const float*)d_in[9];
  const float* bet  = (const float*)d_in[10];
  const float* W3   = (const float*)d_in[11];
  const float* a_s3 = (const float*)d_in[12];
  const float* a_d3 = (const float*)d_in[13];
  const float* b3   = (const float*)d_in[14];
  const float* gam3 = (const float*)d_in[15];
  const float* bet3 = (const float*)d_in[16];
  const float* M1   = (const float*)d_in[17];
  const float* bm1  = (const float*)d_in[18];
  const float* gm1  = (const float*)d_in[19];
  const float* bb1  = (const float*)d_in[20];
  const float* M2   = (const float*)d_in[21];
  const float* bm2  = (const float*)d_in[22];
  const float* gm2  = (const float*)d_in[23];
  const float* bb2  = (const float*)d_in[24];
  const float* M3   = (const float*)d_in[25];
  const float* bm3  = (const float*)d_in[26];
  float* out = (float*)d_out;

  char* ws = (char*)d_ws;
  size_t off = 0;
  auto alloc = [&](size_t bytes)->char*{
    char* p = ws + off; off += (bytes + 255) & ~(size_t)255; return p;
  };
  float* hA     = (float*)alloc((size_t)N_NODESC*DIM*4);
  unsigned short* hp = (unsigned short*)alloc((size_t)N_NODESC*DIM*2);
  float* al_s   = (float*)alloc((size_t)N_NODESC*8*4);
  float* al_d   = (float*)alloc((size_t)N_NODESC*8*4);
  float* esc    = (float*)alloc((size_t)E_TOT*8*4);
  int* row_ptr  = (int*)alloc((size_t)(N_NODESC+1)*4);
  int* deg      = (int*)alloc((size_t)N_NODESC*4);
  int* cursor   = (int*)alloc((size_t)N_NODESC*4);
  int* scanned  = (int*)alloc((size_t)N_NODESC*4);
  int* bsum     = (int*)alloc((size_t)SCAN_NB*4);
  int* col      = (int*)alloc((size_t)E_TOT*4);
  float* bns4   = (float*)alloc(4*2*DIM*4);   // per-layer BN stats
  float* psum   = (float*)alloc((size_t)NGRAPH*DIM*4);
  int* pcnt     = (int*)alloc(NGRAPH*4);
  (void)ws_size; (void)n_in; (void)in_sizes; (void)out_size;

  const int GEMM_GRID = (N_NODESC + 63)/64;                        // 782
  const size_t GEMM_LDS = (KC*SW_STRIDE + KC*SAT_STRIDE + 2*DIM)*4; // 38592 B

  // CSR build (same graph reused by all 4 GAT layers) — parallel scan
  hipMemsetAsync(deg, 0, (size_t)N_NODESC*4, stream);
  hipMemsetAsync(bns4, 0, 4*2*DIM*4, stream);
  k_count<<<(E_TOT+255)/256, 256, 0, stream>>>(ei, deg);
  k_scan1<<<SCAN_NB, 256, 0, stream>>>(deg, scanned, bsum);
  k_scan2<<<1, 128, 0, stream>>>(bsum);
  k_scan3<<<(N_NODESC+255)/256, 256, 0, stream>>>(scanned, bsum, row_ptr, cursor);
  k_scatter<<<(E_TOT+255)/256, 256, 0, stream>>>(ei, cursor, col);

  // embed: hA = x @ We + be (f32 out)
  k_gemm_fused<<<GEMM_GRID, 256, GEMM_LDS, stream>>>(
      x, We, be, nullptr, nullptr, hA, nullptr, nullptr, nullptr, 128, 0,
      nullptr, nullptr, nullptr);

  for (int L=0; L<4; ++L){
    const float* W  = (L<3) ? (Wg  + (size_t)L*DIM*DIM) : W3;
    const float* as = (L<3) ? (a_sg + (size_t)L*8*18)   : a_s3;
    const float* ad = (L<3) ? (a_dg + (size_t)L*8*18)   : a_d3;
    const float* bb = (L<3) ? (bg  + L*DIM) : b3;
    int H = (L<3) ? 8 : 1;
    int C = (L<3) ? 18 : 144;
    // BN of the PREVIOUS layer's output is applied while staging A
    const float* bnp = (L==0) ? nullptr : bns4 + (size_t)(L-1)*2*DIM;
    const float* gmp = (L==0) ? nullptr : gam + (size_t)(L-1)*DIM;
    const float* btp = (L==0) ? nullptr : bet + (size_t)(L-1)*DIM;
    k_gemm_fused<<<GEMM_GRID, 256, GEMM_LDS, stream>>>(
        hA, W, nullptr, as, ad, nullptr, hp, al_s, al_d, DIM, H, bnp, gmp, btp);
    k_edge_softmax<<<(N_NODESC*H+255)/256, 256, 0, stream>>>(
        al_s, al_d, row_ptr, col, esc, H);
    k_aggregate2<<<(N_NODESC*72+255)/256, 256, 0, stream>>>(
        (const unsigned*)hp, esc, row_ptr, col, bb, hA, H, C/2);
    k_bnstats<<<256, 192, 0, stream>>>(hA, bns4 + (size_t)L*2*DIM);
  }

  hipMemsetAsync(psum, 0, (size_t)NGRAPH*DIM*4, stream);
  k_pool<<<NGRAPH*8, 192, 0, stream>>>(hA, batch, psum, pcnt);
  k_mlp<<<1, 256, 0, stream>>>(psum, pcnt, bns4 + 3*2*DIM, gam3, bet3,
                               M1,bm1,gm1,bb1, M2,bm2,gm2,bb2, M3,bm3, out);
}

// Round 7
// 1119.334 us; speedup vs baseline: 1.0594x; 1.0594x over previous
//
#include <hip/hip_runtime.h>
#include <cstdint>

#define N_NODESC 50000
#define N_EDGESC 500000
#define E_TOT    550000
#define DIM      144
#define NGRAPH   64
#define EPSV     1e-5f
#define SCAN_NB  ((N_NODESC + 511)/512)   // 98 blocks of 512 elements

__device__ __forceinline__ float lrelu(float x){ return x > 0.f ? x : 0.2f*x; }

// bf16 round-to-nearest-even pack/unpack
__device__ __forceinline__ unsigned short f2bf(float f){
  unsigned u = __float_as_uint(f);
  u += 0x7FFF + ((u >> 16) & 1);
  return (unsigned short)(u >> 16);
}
__device__ __forceinline__ float bf2f(unsigned short b){
  return __uint_as_float(((unsigned)b) << 16);
}

// ---------------- CSR build (by dst, self-loops appended) ----------------
__global__ void k_count(const int* __restrict__ ei, int* __restrict__ deg){
  int e = blockIdx.x*blockDim.x + threadIdx.x;
  if (e >= E_TOT) return;
  int d = (e < N_EDGESC) ? ei[N_EDGESC + e] : (e - N_EDGESC);
  atomicAdd(&deg[d], 1);
}

__global__ __launch_bounds__(256) void k_scan1(const int* __restrict__ deg,
    int* __restrict__ scanned, int* __restrict__ bsum){
  __shared__ int ls[256];
  int b = blockIdx.x, t = threadIdx.x;
  int i0 = b*512 + 2*t;
  int e0 = (i0   < N_NODESC) ? deg[i0]   : 0;
  int e1 = (i0+1 < N_NODESC) ? deg[i0+1] : 0;
  int s = e0 + e1;
  ls[t] = s;
  __syncthreads();
  #pragma unroll
  for (int ofs=1; ofs<256; ofs<<=1){
    int v = (t >= ofs) ? ls[t-ofs] : 0;
    __syncthreads();
    ls[t] += v;
    __syncthreads();
  }
  int excl = ls[t] - s;
  if (i0   < N_NODESC) scanned[i0]   = excl;
  if (i0+1 < N_NODESC) scanned[i0+1] = excl + e0;
  if (t == 255) bsum[b] = ls[255];
}

__global__ void k_scan2(int* __restrict__ bsum){
  __shared__ int ls[128];
  int t = threadIdx.x;
  int v = (t < SCAN_NB) ? bsum[t] : 0;
  ls[t] = v;
  __syncthreads();
  #pragma unroll
  for (int ofs=1; ofs<128; ofs<<=1){
    int u = (t >= ofs) ? ls[t-ofs] : 0;
    __syncthreads();
    ls[t] += u;
    __syncthreads();
  }
  if (t < SCAN_NB) bsum[t] = ls[t] - v;
}

__global__ __launch_bounds__(256) void k_scan3(const int* __restrict__ scanned,
    const int* __restrict__ bsum, int* __restrict__ row_ptr, int* __restrict__ cursor){
  int i = blockIdx.x*blockDim.x + threadIdx.x;
  if (i < N_NODESC){
    int v = scanned[i] + bsum[i >> 9];
    row_ptr[i] = v; cursor[i] = v;
  }
  if (i == 0) row_ptr[N_NODESC] = E_TOT;
}

__global__ void k_scatter(const int* __restrict__ ei, int* __restrict__ cursor,
                          int* __restrict__ col){
  int e = blockIdx.x*blockDim.x + threadIdx.x;
  if (e >= E_TOT) return;
  int s, d;
  if (e < N_EDGESC){ s = ei[e]; d = ei[N_EDGESC + e]; } else { s = e - N_EDGESC; d = s; }
  int pos = atomicAdd(&cursor[d], 1);
  col[pos] = s;
}

// ---------------- fused GEMM + BN-on-input + attention logits ----------------
#define KC 36
#define SW_STRIDE 192   // 16 groups * 12
#define SAT_STRIDE 68
__global__ __launch_bounds__(256) void k_gemm_fused(
    const float* __restrict__ A, const float* __restrict__ W,
    const float* __restrict__ bias,
    const float* __restrict__ a_s, const float* __restrict__ a_d,
    float* __restrict__ outf, unsigned short* __restrict__ outb,
    float* __restrict__ al_s, float* __restrict__ al_d,
    int K, int H,
    const float* __restrict__ bnsum, const float* __restrict__ bngam,
    const float* __restrict__ bnbet){
  extern __shared__ float smem[];
  float* sW  = smem;                 // KC * 192
  float* sAT = smem + KC*SW_STRIDE;  // KC * 68
  float* sBN = sAT + KC*SAT_STRIDE;  // 2*144 (scale, shift)
  int t = threadIdx.x;
  int m0 = blockIdx.x * 64;
  int rg = t & 15, cg = t >> 4;
  int c0 = cg * 9;

  if (bnsum){
    for (int i=t; i<K; i+=256){
      float mu  = bnsum[i] * (1.f/N_NODESC);
      float var = bnsum[K+i] * (1.f/N_NODESC) - mu*mu;
      float inv = rsqrtf(var + EPSV);
      float sc = inv * bngam[i];
      sBN[i] = sc; sBN[K+i] = bnbet[i] - mu*sc;
    }
    __syncthreads();
  }

  float acc[4][9];
  #pragma unroll
  for (int i=0;i<4;++i)
    #pragma unroll
    for (int j=0;j<9;++j) acc[i][j] = bias ? bias[c0+j] : 0.f;

  for (int k0 = 0; k0 < K; k0 += KC){
    int kc = min(KC, K - k0);
    __syncthreads();
    for (int i = t; i < kc*144; i += 256){
      int kk = i / 144, c = i - kk*144;
      int g = c / 9, j = c - g*9;
      sW[kk*SW_STRIDE + g*12 + j] = W[(size_t)(k0+kk)*144 + c];
    }
    for (int i = t; i < 64*kc; i += 256){
      int r = i / kc, kk = i - r*kc;
      int m = m0 + r; if (m >= N_NODESC) m = N_NODESC - 1;
      float v = A[(size_t)m*K + k0 + kk];
      if (bnsum) v = fmaf(v, sBN[k0+kk], sBN[K+k0+kk]);
      sAT[kk*SAT_STRIDE + r] = v;
    }
    __syncthreads();
    for (int k = 0; k < kc; ++k){
      float4 a4 = *(const float4*)&sAT[k*SAT_STRIDE + rg*4];
      const float* wp = &sW[k*SW_STRIDE + cg*12];
      float4 w0 = *(const float4*)(wp);
      float4 w1 = *(const float4*)(wp+4);
      float  w8 = wp[8];
      float av[4] = {a4.x, a4.y, a4.z, a4.w};
      float wv[9] = {w0.x,w0.y,w0.z,w0.w,w1.x,w1.y,w1.z,w1.w,w8};
      #pragma unroll
      for (int i=0;i<4;++i)
        #pragma unroll
        for (int j=0;j<9;++j) acc[i][j] = fmaf(av[i], wv[j], acc[i][j]);
    }
  }

  if (H > 0){
    __syncthreads();
    float* sRs = smem;
    float* sRd = smem + 64*17;
    float ps[4], pd[4];
    #pragma unroll
    for (int i=0;i<4;++i){ ps[i]=0.f; pd[i]=0.f; }
    #pragma unroll
    for (int j=0;j<9;++j){
      float asj = a_s[c0+j], adj = a_d[c0+j];
      #pragma unroll
      for (int i=0;i<4;++i){ ps[i] = fmaf(acc[i][j], asj, ps[i]); pd[i] = fmaf(acc[i][j], adj, pd[i]); }
    }
    #pragma unroll
    for (int i=0;i<4;++i){
      sRs[(rg*4+i)*17 + cg] = ps[i];
      sRd[(rg*4+i)*17 + cg] = pd[i];
    }
    __syncthreads();
    int G = 16 / H;
    for (int idx = t; idx < 64*H; idx += 256){
      int r = idx / H, h = idx - r*H;
      float ss = 0.f, sd = 0.f;
      for (int g2 = h*G; g2 < (h+1)*G; ++g2){ ss += sRs[r*17+g2]; sd += sRd[r*17+g2]; }
      int m = m0 + r;
      if (m < N_NODESC){ al_s[m*H+h] = ss; al_d[m*H+h] = sd; }
    }
  }

  #pragma unroll
  for (int i=0;i<4;++i){
    int m = m0 + rg*4 + i;
    if (m < N_NODESC){
      if (outb){
        unsigned short* o = outb + (size_t)m*DIM + c0;
        #pragma unroll
        for (int j=0;j<9;++j) o[j] = f2bf(acc[i][j]);
      } else {
        float* o = outf + (size_t)m*DIM + c0;
        #pragma unroll
        for (int j=0;j<9;++j) o[j] = acc[i][j];
      }
    }
  }
}

// ---------------- segment softmax: one thread per (node, head) ----------------
__global__ __launch_bounds__(256) void k_edge_softmax(
    const float* __restrict__ al_s, const float* __restrict__ al_d,
    const int* __restrict__ row_ptr, const int* __restrict__ col,
    float* __restrict__ esc, int H){
  int idx = blockIdx.x*blockDim.x + threadIdx.x;
  if (idx >= N_NODESC*H) return;
  int n = idx / H, h = idx - n*H;
  int p0 = row_ptr[n], p1 = row_ptr[n+1];
  float ald = al_d[idx];
  float m = -3.4e38f;
  for (int e = p0; e < p1; ++e){
    float sc = lrelu(al_s[col[e]*H + h] + ald);
    esc[(size_t)e*H + h] = sc;
    m = fmaxf(m, sc);
  }
  float den = 0.f;
  for (int e = p0; e < p1; ++e) den += __expf(esc[(size_t)e*H + h] - m);
  float inv = 1.f/(den + 1e-16f);
  for (int e = p0; e < p1; ++e)
    esc[(size_t)e*H + h] = __expf(esc[(size_t)e*H + h] - m) * inv;
}

// ---------------- weighted gather: one thread per (node, channel-pair) ----------------
__global__ __launch_bounds__(256) void k_aggregate2(
    const unsigned* __restrict__ hp2, const float* __restrict__ w,
    const int* __restrict__ row_ptr, const int* __restrict__ col,
    const float* __restrict__ bias, float* __restrict__ out,
    int H, int C2){             // C2 = C/2 (9 for 8-head, 72 for 1-head)
  int idx = blockIdx.x*blockDim.x + threadIdx.x;
  if (idx >= N_NODESC*72) return;
  int n = idx / 72, cp = idx - n*72;
  int h = cp / C2;
  int p0 = row_ptr[n], p1 = row_ptr[n+1];
  float a0 = 0.f, a1 = 0.f;
  for (int e = p0; e < p1; ++e){
    int s = col[e];
    float wgt = w[(size_t)e*H + h];
    unsigned v = hp2[(size_t)s*72 + cp];
    a0 = fmaf(wgt, __uint_as_float(v << 16), a0);
    a1 = fmaf(wgt, __uint_as_float(v & 0xFFFF0000u), a1);
  }
  int c0 = 2*cp;
  float2 r;
  r.x = fmaxf(a0 + bias[c0],   0.f);
  r.y = fmaxf(a1 + bias[c0+1], 0.f);
  *(float2*)&out[(size_t)n*DIM + c0] = r;
}

// ---------------- batchnorm stats: register accumulate, coalesced ----------------
__global__ __launch_bounds__(192) void k_bnstats(const float* __restrict__ h,
                                                 float* __restrict__ sums){
  int t = threadIdx.x;
  if (t >= DIM) return;
  int rows = (N_NODESC + gridDim.x - 1)/gridDim.x;
  int n0 = blockIdx.x*rows, n1 = min(N_NODESC, n0+rows);
  float s = 0.f, q = 0.f;
  for (int n = n0; n < n1; ++n){
    float v = h[(size_t)n*DIM + t];
    s += v; q += v*v;
  }
  atomicAdd(&sums[t], s);
  atomicAdd(&sums[DIM+t], q);
}

// ---------------- per-graph mean pool (batch is sorted) ----------------
__device__ int lbound(const int* a, int n, int v){
  int lo = 0, hi = n;
  while (lo < hi){ int m = (lo+hi) >> 1; if (a[m] < v) lo = m+1; else hi = m; }
  return lo;
}

__global__ __launch_bounds__(192) void k_pool(const float* __restrict__ h,
    const int* __restrict__ batch, float* __restrict__ sums, int* __restrict__ cnts){
  int g = blockIdx.x & 63, part = blockIdx.x >> 6;     // 8 parts per graph
  __shared__ int sb[2];
  if (threadIdx.x == 0){ sb[0] = lbound(batch, N_NODESC, g); sb[1] = lbound(batch, N_NODESC, g+1); }
  __syncthreads();
  int lo = sb[0], hi = sb[1];
  int t = threadIdx.x;
  if (t < DIM){
    float acc = 0.f;
    for (int n = lo + part; n < hi; n += 8) acc += h[(size_t)n*DIM + t];
    atomicAdd(&sums[g*DIM + t], acc);
  }
  if (t == 0 && part == 0) cnts[g] = hi - lo;
}

// ---------------- MLP head: column-parallel, BN via wave reduction ----------------
// Layer1: 72 blocks x 64 threads. thread=graph row, block=output column.
__global__ __launch_bounds__(64) void k_mlp1(const float* __restrict__ psum,
    const int* __restrict__ cnts,
    const float* __restrict__ bn3, const float* __restrict__ gam3,
    const float* __restrict__ bet3,
    const float* __restrict__ M1, const float* __restrict__ bm1,
    const float* __restrict__ gm1, const float* __restrict__ bb1,
    float* __restrict__ h1){
  __shared__ float sSc[144], sSh[144];
  int t = threadIdx.x, c = blockIdx.x;
  for (int i=t; i<144; i+=64){
    float mu  = bn3[i] * (1.f/N_NODESC);
    float var = bn3[144+i] * (1.f/N_NODESC) - mu*mu;
    float sc  = rsqrtf(var + EPSV) * gam3[i];
    sSc[i] = sc; sSh[i] = bet3[i] - mu*sc;
  }
  __syncthreads();
  float invc = 1.f / (float)max(cnts[t], 1);
  float acc = bm1[c];
  const float* pr = psum + t*144;
  for (int k=0; k<144; ++k){
    float g = fmaf(pr[k]*invc, sSc[k], sSh[k]);
    acc = fmaf(g, M1[k*72 + c], acc);
  }
  // BN over the 64 rows (one wave) via shuffle butterfly
  float s = acc, q = acc*acc;
  #pragma unroll
  for (int o=32; o>0; o>>=1){ s += __shfl_xor(s, o, 64); q += __shfl_xor(q, o, 64); }
  float mu = s*(1.f/64.f), var = q*(1.f/64.f) - mu*mu;
  float v = (acc - mu)*rsqrtf(var + EPSV)*gm1[c] + bb1[c];
  h1[t*72 + c] = fmaxf(v, 0.f);
}

// Layer2: 36 blocks x 64 threads.
__global__ __launch_bounds__(64) void k_mlp2(const float* __restrict__ h1,
    const float* __restrict__ M2, const float* __restrict__ bm2,
    const float* __restrict__ gm2, const float* __restrict__ bb2,
    float* __restrict__ h2){
  int t = threadIdx.x, c = blockIdx.x;
  float acc = bm2[c];
  const float* pr = h1 + t*72;
  for (int k=0; k<72; ++k) acc = fmaf(pr[k], M2[k*36 + c], acc);
  float s = acc, q = acc*acc;
  #pragma unroll
  for (int o=32; o>0; o>>=1){ s += __shfl_xor(s, o, 64); q += __shfl_xor(q, o, 64); }
  float mu = s*(1.f/64.f), var = q*(1.f/64.f) - mu*mu;
  float v = (acc - mu)*rsqrtf(var + EPSV)*gm2[c] + bb2[c];
  h2[t*36 + c] = fmaxf(v, 0.f);
}

// Layer3: 112 blocks x 64 threads (plain linear).
__global__ __launch_bounds__(64) void k_mlp3(const float* __restrict__ h2,
    const float* __restrict__ M3, const float* __restrict__ bm3,
    float* __restrict__ out){
  int t = threadIdx.x, c = blockIdx.x;
  float acc = bm3[c];
  const float* pr = h2 + t*36;
  for (int k=0; k<36; ++k) acc = fmaf(pr[k], M3[k*112 + c], acc);
  out[t*112 + c] = acc;
}

extern "C" void kernel_launch(void* const* d_in, const int* in_sizes, int n_in,
                              void* d_out, int out_size, void* d_ws, size_t ws_size,
                              hipStream_t stream){
  const float* x    = (const float*)d_in[0];
  const int*   ei   = (const int*)d_in[1];
  const int*   batch= (const int*)d_in[2];
  const float* We   = (const float*)d_in[3];
  const float* be   = (const float*)d_in[4];
  const float* Wg   = (const float*)d_in[5];
  const float* a_sg = (const float*)d_in[6];
  const float* a_dg = (const float*)d_in[7];
  const float* bg   = (const float*)d_in[8];
  const float* gam  = (const float*)d_in[9];
  const float* bet  = (const float*)d_in[10];
  const float* W3   = (const float*)d_in[11];
  const float* a_s3 = (const float*)d_in[12];
  const float* a_d3 = (const float*)d_in[13];
  const float* b3   = (const float*)d_in[14];
  const float* gam3 = (const float*)d_in[15];
  const float* bet3 = (const float*)d_in[16];
  const float* M1   = (const float*)d_in[17];
  const float* bm1  = (const float*)d_in[18];
  const float* gm1  = (const float*)d_in[19];
  const float* bb1  = (const float*)d_in[20];
  const float* M2   = (const float*)d_in[21];
  const float* bm2  = (const float*)d_in[22];
  const float* gm2  = (const float*)d_in[23];
  const float* bb2  = (const float*)d_in[24];
  const float* M3   = (const float*)d_in[25];
  const float* bm3  = (const float*)d_in[26];
  float* out = (float*)d_out;

  char* ws = (char*)d_ws;
  size_t off = 0;
  auto alloc = [&](size_t bytes)->char*{
    char* p = ws + off; off += (bytes + 255) & ~(size_t)255; return p;
  };
  float* hA     = (float*)alloc((size_t)N_NODESC*DIM*4);
  unsigned short* hp = (unsigned short*)alloc((size_t)N_NODESC*DIM*2);
  float* al_s   = (float*)alloc((size_t)N_NODESC*8*4);
  float* al_d   = (float*)alloc((size_t)N_NODESC*8*4);
  float* esc    = (float*)alloc((size_t)E_TOT*8*4);
  int* row_ptr  = (int*)alloc((size_t)(N_NODESC+1)*4);
  int* deg      = (int*)alloc((size_t)N_NODESC*4);
  int* cursor   = (int*)alloc((size_t)N_NODESC*4);
  int* scanned  = (int*)alloc((size_t)N_NODESC*4);
  int* bsum     = (int*)alloc((size_t)SCAN_NB*4);
  int* col      = (int*)alloc((size_t)E_TOT*4);
  float* bns4   = (float*)alloc(4*2*DIM*4);   // per-layer BN stats
  float* psum   = (float*)alloc((size_t)NGRAPH*DIM*4);
  int* pcnt     = (int*)alloc(NGRAPH*4);
  float* h1buf  = (float*)alloc((size_t)NGRAPH*72*4);
  float* h2buf  = (float*)alloc((size_t)NGRAPH*36*4);
  (void)ws_size; (void)n_in; (void)in_sizes; (void)out_size;

  const int GEMM_GRID = (N_NODESC + 63)/64;                        // 782
  const size_t GEMM_LDS = (KC*SW_STRIDE + KC*SAT_STRIDE + 2*DIM)*4; // 38592 B

  // CSR build (same graph reused by all 4 GAT layers) — parallel scan
  hipMemsetAsync(deg, 0, (size_t)N_NODESC*4, stream);
  hipMemsetAsync(bns4, 0, 4*2*DIM*4, stream);
  k_count<<<(E_TOT+255)/256, 256, 0, stream>>>(ei, deg);
  k_scan1<<<SCAN_NB, 256, 0, stream>>>(deg, scanned, bsum);
  k_scan2<<<1, 128, 0, stream>>>(bsum);
  k_scan3<<<(N_NODESC+255)/256, 256, 0, stream>>>(scanned, bsum, row_ptr, cursor);
  k_scatter<<<(E_TOT+255)/256, 256, 0, stream>>>(ei, cursor, col);

  // embed: hA = x @ We + be (f32 out)
  k_gemm_fused<<<GEMM_GRID, 256, GEMM_LDS, stream>>>(
      x, We, be, nullptr, nullptr, hA, nullptr, nullptr, nullptr, 128, 0,
      nullptr, nullptr, nullptr);

  for (int L=0; L<4; ++L){
    const float* W  = (L<3) ? (Wg  + (size_t)L*DIM*DIM) : W3;
    const float* as = (L<3) ? (a_sg + (size_t)L*8*18)   : a_s3;
    const float* ad = (L<3) ? (a_dg + (size_t)L*8*18)   : a_d3;
    const float* bb = (L<3) ? (bg  + L*DIM) : b3;
    int H = (L<3) ? 8 : 1;
    int C = (L<3) ? 18 : 144;
    // BN of the PREVIOUS layer's output is applied while staging A
    const float* bnp = (L==0) ? nullptr : bns4 + (size_t)(L-1)*2*DIM;
    const float* gmp = (L==0) ? nullptr : gam + (size_t)(L-1)*DIM;
    const float* btp = (L==0) ? nullptr : bet + (size_t)(L-1)*DIM;
    k_gemm_fused<<<GEMM_GRID, 256, GEMM_LDS, stream>>>(
        hA, W, nullptr, as, ad, nullptr, hp, al_s, al_d, DIM, H, bnp, gmp, btp);
    k_edge_softmax<<<(N_NODESC*H+255)/256, 256, 0, stream>>>(
        al_s, al_d, row_ptr, col, esc, H);
    k_aggregate2<<<(N_NODESC*72+255)/256, 256, 0, stream>>>(
        (const unsigned*)hp, esc, row_ptr, col, bb, hA, H, C/2);
    k_bnstats<<<256, 192, 0, stream>>>(hA, bns4 + (size_t)L*2*DIM);
  }

  hipMemsetAsync(psum, 0, (size_t)NGRAPH*DIM*4, stream);
  k_pool<<<NGRAPH*8, 192, 0, stream>>>(hA, batch, psum, pcnt);
  k_mlp1<<<72, 64, 0, stream>>>(psum, pcnt, bns4 + 3*2*DIM, gam3, bet3,
                                M1, bm1, gm1, bb1, h1buf);
  k_mlp2<<<36, 64, 0, stream>>>(h1buf, M2, bm2, gm2, bb2, h2buf);
  k_mlp3<<<112, 64, 0, stream>>>(h2buf, M3, bm3, out);
}

// Round 8
// 991.211 us; speedup vs baseline: 1.1963x; 1.1293x over previous
//
#include <hip/hip_runtime.h>
#include <cstdint>

#define N_NODESC 50000
#define N_EDGESC 500000
#define E_TOT    550000
#define DIM      144
#define NGRAPH   64
#define EPSV     1e-5f
#define SCAN_NB  ((N_NODESC + 511)/512)   // 98 blocks of 512 elements

__device__ __forceinline__ float lrelu(float x){ return x > 0.f ? x : 0.2f*x; }

// bf16 round-to-nearest-even pack/unpack
__device__ __forceinline__ unsigned short f2bf(float f){
  unsigned u = __float_as_uint(f);
  u += 0x7FFF + ((u >> 16) & 1);
  return (unsigned short)(u >> 16);
}
__device__ __forceinline__ float bf2f(unsigned short b){
  return __uint_as_float(((unsigned)b) << 16);
}

// ---------------- CSR build (by dst, self-loops appended) ----------------
__global__ void k_count(const int* __restrict__ ei, int* __restrict__ deg){
  int e = blockIdx.x*blockDim.x + threadIdx.x;
  if (e >= E_TOT) return;
  int d = (e < N_EDGESC) ? ei[N_EDGESC + e] : (e - N_EDGESC);
  atomicAdd(&deg[d], 1);
}

__global__ __launch_bounds__(256) void k_scan1(const int* __restrict__ deg,
    int* __restrict__ scanned, int* __restrict__ bsum){
  __shared__ int ls[256];
  int b = blockIdx.x, t = threadIdx.x;
  int i0 = b*512 + 2*t;
  int e0 = (i0   < N_NODESC) ? deg[i0]   : 0;
  int e1 = (i0+1 < N_NODESC) ? deg[i0+1] : 0;
  int s = e0 + e1;
  ls[t] = s;
  __syncthreads();
  #pragma unroll
  for (int ofs=1; ofs<256; ofs<<=1){
    int v = (t >= ofs) ? ls[t-ofs] : 0;
    __syncthreads();
    ls[t] += v;
    __syncthreads();
  }
  int excl = ls[t] - s;
  if (i0   < N_NODESC) scanned[i0]   = excl;
  if (i0+1 < N_NODESC) scanned[i0+1] = excl + e0;
  if (t == 255) bsum[b] = ls[255];
}

__global__ void k_scan2(int* __restrict__ bsum){
  __shared__ int ls[128];
  int t = threadIdx.x;
  int v = (t < SCAN_NB) ? bsum[t] : 0;
  ls[t] = v;
  __syncthreads();
  #pragma unroll
  for (int ofs=1; ofs<128; ofs<<=1){
    int u = (t >= ofs) ? ls[t-ofs] : 0;
    __syncthreads();
    ls[t] += u;
    __syncthreads();
  }
  if (t < SCAN_NB) bsum[t] = ls[t] - v;
}

__global__ __launch_bounds__(256) void k_scan3(const int* __restrict__ scanned,
    const int* __restrict__ bsum, int* __restrict__ row_ptr, int* __restrict__ cursor){
  int i = blockIdx.x*blockDim.x + threadIdx.x;
  if (i < N_NODESC){
    int v = scanned[i] + bsum[i >> 9];
    row_ptr[i] = v; cursor[i] = v;
  }
  if (i == 0) row_ptr[N_NODESC] = E_TOT;
}

__global__ void k_scatter(const int* __restrict__ ei, int* __restrict__ cursor,
                          int* __restrict__ col){
  int e = blockIdx.x*blockDim.x + threadIdx.x;
  if (e >= E_TOT) return;
  int s, d;
  if (e < N_EDGESC){ s = ei[e]; d = ei[N_EDGESC + e]; } else { s = e - N_EDGESC; d = s; }
  int pos = atomicAdd(&cursor[d], 1);
  col[pos] = s;
}

// ---------------- fused GEMM + BN-on-input + attention logits ----------------
#define KC 36
#define SW_STRIDE 192   // 16 groups * 12
#define SAT_STRIDE 68
__global__ __launch_bounds__(256) void k_gemm_fused(
    const float* __restrict__ A, const float* __restrict__ W,
    const float* __restrict__ bias,
    const float* __restrict__ a_s, const float* __restrict__ a_d,
    float* __restrict__ outf, unsigned short* __restrict__ outb,
    float* __restrict__ al_s, float* __restrict__ al_d,
    int K, int H,
    const float* __restrict__ bnsum, const float* __restrict__ bngam,
    const float* __restrict__ bnbet){
  extern __shared__ float smem[];
  float* sW  = smem;                 // KC * 192
  float* sAT = smem + KC*SW_STRIDE;  // KC * 68
  float* sBN = sAT + KC*SAT_STRIDE;  // 2*144 (scale, shift)
  int t = threadIdx.x;
  int m0 = blockIdx.x * 64;
  int rg = t & 15, cg = t >> 4;
  int c0 = cg * 9;

  if (bnsum){
    for (int i=t; i<K; i+=256){
      float mu  = bnsum[i] * (1.f/N_NODESC);
      float var = bnsum[K+i] * (1.f/N_NODESC) - mu*mu;
      float inv = rsqrtf(var + EPSV);
      float sc = inv * bngam[i];
      sBN[i] = sc; sBN[K+i] = bnbet[i] - mu*sc;
    }
    __syncthreads();
  }

  float acc[4][9];
  #pragma unroll
  for (int i=0;i<4;++i)
    #pragma unroll
    for (int j=0;j<9;++j) acc[i][j] = bias ? bias[c0+j] : 0.f;

  for (int k0 = 0; k0 < K; k0 += KC){
    int kc = min(KC, K - k0);
    __syncthreads();
    for (int i = t; i < kc*144; i += 256){
      int kk = i / 144, c = i - kk*144;
      int g = c / 9, j = c - g*9;
      sW[kk*SW_STRIDE + g*12 + j] = W[(size_t)(k0+kk)*144 + c];
    }
    for (int i = t; i < 64*kc; i += 256){
      int r = i / kc, kk = i - r*kc;
      int m = m0 + r; if (m >= N_NODESC) m = N_NODESC - 1;
      float v = A[(size_t)m*K + k0 + kk];
      if (bnsum) v = fmaf(v, sBN[k0+kk], sBN[K+k0+kk]);
      sAT[kk*SAT_STRIDE + r] = v;
    }
    __syncthreads();
    for (int k = 0; k < kc; ++k){
      float4 a4 = *(const float4*)&sAT[k*SAT_STRIDE + rg*4];
      const float* wp = &sW[k*SW_STRIDE + cg*12];
      float4 w0 = *(const float4*)(wp);
      float4 w1 = *(const float4*)(wp+4);
      float  w8 = wp[8];
      float av[4] = {a4.x, a4.y, a4.z, a4.w};
      float wv[9] = {w0.x,w0.y,w0.z,w0.w,w1.x,w1.y,w1.z,w1.w,w8};
      #pragma unroll
      for (int i=0;i<4;++i)
        #pragma unroll
        for (int j=0;j<9;++j) acc[i][j] = fmaf(av[i], wv[j], acc[i][j]);
    }
  }

  if (H > 0){
    __syncthreads();
    float* sRs = smem;
    float* sRd = smem + 64*17;
    float ps[4], pd[4];
    #pragma unroll
    for (int i=0;i<4;++i){ ps[i]=0.f; pd[i]=0.f; }
    #pragma unroll
    for (int j=0;j<9;++j){
      float asj = a_s[c0+j], adj = a_d[c0+j];
      #pragma unroll
      for (int i=0;i<4;++i){ ps[i] = fmaf(acc[i][j], asj, ps[i]); pd[i] = fmaf(acc[i][j], adj, pd[i]); }
    }
    #pragma unroll
    for (int i=0;i<4;++i){
      sRs[(rg*4+i)*17 + cg] = ps[i];
      sRd[(rg*4+i)*17 + cg] = pd[i];
    }
    __syncthreads();
    int G = 16 / H;
    for (int idx = t; idx < 64*H; idx += 256){
      int r = idx / H, h = idx - r*H;
      float ss = 0.f, sd = 0.f;
      for (int g2 = h*G; g2 < (h+1)*G; ++g2){ ss += sRs[r*17+g2]; sd += sRd[r*17+g2]; }
      int m = m0 + r;
      if (m < N_NODESC){ al_s[m*H+h] = ss; al_d[m*H+h] = sd; }
    }
  }

  #pragma unroll
  for (int i=0;i<4;++i){
    int m = m0 + rg*4 + i;
    if (m < N_NODESC){
      if (outb){
        unsigned short* o = outb + (size_t)m*DIM + c0;
        #pragma unroll
        for (int j=0;j<9;++j) o[j] = f2bf(acc[i][j]);
      } else {
        float* o = outf + (size_t)m*DIM + c0;
        #pragma unroll
        for (int j=0;j<9;++j) o[j] = acc[i][j];
      }
    }
  }
}

// ---------------- segment softmax: one thread per (node, head) ----------------
// Pass 1 uses batched prefetch (8 independent col loads, then 8 al_s gathers)
// to keep ~8 loads in flight instead of a serial 2-deep chain per edge.
#define EB 8
__global__ __launch_bounds__(256) void k_edge_softmax(
    const float* __restrict__ al_s, const float* __restrict__ al_d,
    const int* __restrict__ row_ptr, const int* __restrict__ col,
    float* __restrict__ esc, int H){
  int idx = blockIdx.x*blockDim.x + threadIdx.x;
  if (idx >= N_NODESC*H) return;
  int n = idx / H, h = idx - n*H;
  int p0 = row_ptr[n], p1 = row_ptr[n+1];
  float ald = al_d[idx];
  float m = -3.4e38f;
  for (int base = p0; base < p1; base += EB){
    int cnt = min(EB, p1 - base);
    int ss[EB];
    #pragma unroll
    for (int i=0;i<EB;++i) if (i<cnt) ss[i] = col[base+i];
    float sc[EB];
    #pragma unroll
    for (int i=0;i<EB;++i) if (i<cnt) sc[i] = lrelu(al_s[ss[i]*H + h] + ald);
    #pragma unroll
    for (int i=0;i<EB;++i) if (i<cnt){
      esc[(size_t)(base+i)*H + h] = sc[i];
      m = fmaxf(m, sc[i]);
    }
  }
  float den = 0.f;
  for (int e = p0; e < p1; ++e) den += __expf(esc[(size_t)e*H + h] - m);
  float inv = 1.f/(den + 1e-16f);
  for (int e = p0; e < p1; ++e)
    esc[(size_t)e*H + h] = __expf(esc[(size_t)e*H + h] - m) * inv;
}

// ---------------- weighted gather: one thread per (node, channel-pair) ----------------
// Batched prefetch: chunk of 8 edges -> 16 independent col/w loads, then 8
// independent hp2 gathers in flight, then FMAs.
__global__ __launch_bounds__(256) void k_aggregate2(
    const unsigned* __restrict__ hp2, const float* __restrict__ w,
    const int* __restrict__ row_ptr, const int* __restrict__ col,
    const float* __restrict__ bias, float* __restrict__ out,
    int H, int C2){             // C2 = C/2 (9 for 8-head, 72 for 1-head)
  int idx = blockIdx.x*blockDim.x + threadIdx.x;
  if (idx >= N_NODESC*72) return;
  int n = idx / 72, cp = idx - n*72;
  int h = cp / C2;
  int p0 = row_ptr[n], p1 = row_ptr[n+1];
  float a0 = 0.f, a1 = 0.f;
  for (int base = p0; base < p1; base += EB){
    int cnt = min(EB, p1 - base);
    int ss[EB]; float ww[EB];
    #pragma unroll
    for (int i=0;i<EB;++i) if (i<cnt){
      ss[i] = col[base+i];
      ww[i] = w[(size_t)(base+i)*H + h];
    }
    unsigned vv[EB];
    #pragma unroll
    for (int i=0;i<EB;++i) if (i<cnt) vv[i] = hp2[(size_t)ss[i]*72 + cp];
    #pragma unroll
    for (int i=0;i<EB;++i) if (i<cnt){
      a0 = fmaf(ww[i], __uint_as_float(vv[i] << 16), a0);
      a1 = fmaf(ww[i], __uint_as_float(vv[i] & 0xFFFF0000u), a1);
    }
  }
  int c0 = 2*cp;
  float2 r;
  r.x = fmaxf(a0 + bias[c0],   0.f);
  r.y = fmaxf(a1 + bias[c0+1], 0.f);
  *(float2*)&out[(size_t)n*DIM + c0] = r;
}

// ---------------- batchnorm stats: register accumulate, coalesced ----------------
__global__ __launch_bounds__(192) void k_bnstats(const float* __restrict__ h,
                                                 float* __restrict__ sums){
  int t = threadIdx.x;
  if (t >= DIM) return;
  int rows = (N_NODESC + gridDim.x - 1)/gridDim.x;
  int n0 = blockIdx.x*rows, n1 = min(N_NODESC, n0+rows);
  float s = 0.f, q = 0.f;
  for (int n = n0; n < n1; ++n){
    float v = h[(size_t)n*DIM + t];
    s += v; q += v*v;
  }
  atomicAdd(&sums[t], s);
  atomicAdd(&sums[DIM+t], q);
}

// ---------------- per-graph mean pool (batch is sorted) ----------------
__device__ int lbound(const int* a, int n, int v){
  int lo = 0, hi = n;
  while (lo < hi){ int m = (lo+hi) >> 1; if (a[m] < v) lo = m+1; else hi = m; }
  return lo;
}

__global__ __launch_bounds__(192) void k_pool(const float* __restrict__ h,
    const int* __restrict__ batch, float* __restrict__ sums, int* __restrict__ cnts){
  int g = blockIdx.x & 63, part = blockIdx.x >> 6;     // 8 parts per graph
  __shared__ int sb[2];
  if (threadIdx.x == 0){ sb[0] = lbound(batch, N_NODESC, g); sb[1] = lbound(batch, N_NODESC, g+1); }
  __syncthreads();
  int lo = sb[0], hi = sb[1];
  int t = threadIdx.x;
  if (t < DIM){
    float acc = 0.f;
    for (int n = lo + part; n < hi; n += 8) acc += h[(size_t)n*DIM + t];
    atomicAdd(&sums[g*DIM + t], acc);
  }
  if (t == 0 && part == 0) cnts[g] = hi - lo;
}

// ---------------- MLP head: column-parallel, BN via wave reduction ----------------
__global__ __launch_bounds__(64) void k_mlp1(const float* __restrict__ psum,
    const int* __restrict__ cnts,
    const float* __restrict__ bn3, const float* __restrict__ gam3,
    const float* __restrict__ bet3,
    const float* __restrict__ M1, const float* __restrict__ bm1,
    const float* __restrict__ gm1, const float* __restrict__ bb1,
    float* __restrict__ h1){
  __shared__ float sSc[144], sSh[144];
  int t = threadIdx.x, c = blockIdx.x;
  for (int i=t; i<144; i+=64){
    float mu  = bn3[i] * (1.f/N_NODESC);
    float var = bn3[144+i] * (1.f/N_NODESC) - mu*mu;
    float sc  = rsqrtf(var + EPSV) * gam3[i];
    sSc[i] = sc; sSh[i] = bet3[i] - mu*sc;
  }
  __syncthreads();
  float invc = 1.f / (float)max(cnts[t], 1);
  float acc = bm1[c];
  const float* pr = psum + t*144;
  for (int k=0; k<144; ++k){
    float g = fmaf(pr[k]*invc, sSc[k], sSh[k]);
    acc = fmaf(g, M1[k*72 + c], acc);
  }
  float s = acc, q = acc*acc;
  #pragma unroll
  for (int o=32; o>0; o>>=1){ s += __shfl_xor(s, o, 64); q += __shfl_xor(q, o, 64); }
  float mu = s*(1.f/64.f), var = q*(1.f/64.f) - mu*mu;
  float v = (acc - mu)*rsqrtf(var + EPSV)*gm1[c] + bb1[c];
  h1[t*72 + c] = fmaxf(v, 0.f);
}

__global__ __launch_bounds__(64) void k_mlp2(const float* __restrict__ h1,
    const float* __restrict__ M2, const float* __restrict__ bm2,
    const float* __restrict__ gm2, const float* __restrict__ bb2,
    float* __restrict__ h2){
  int t = threadIdx.x, c = blockIdx.x;
  float acc = bm2[c];
  const float* pr = h1 + t*72;
  for (int k=0; k<72; ++k) acc = fmaf(pr[k], M2[k*36 + c], acc);
  float s = acc, q = acc*acc;
  #pragma unroll
  for (int o=32; o>0; o>>=1){ s += __shfl_xor(s, o, 64); q += __shfl_xor(q, o, 64); }
  float mu = s*(1.f/64.f), var = q*(1.f/64.f) - mu*mu;
  float v = (acc - mu)*rsqrtf(var + EPSV)*gm2[c] + bb2[c];
  h2[t*36 + c] = fmaxf(v, 0.f);
}

__global__ __launch_bounds__(64) void k_mlp3(const float* __restrict__ h2,
    const float* __restrict__ M3, const float* __restrict__ bm3,
    float* __restrict__ out){
  int t = threadIdx.x, c = blockIdx.x;
  float acc = bm3[c];
  const float* pr = h2 + t*36;
  for (int k=0; k<36; ++k) acc = fmaf(pr[k], M3[k*112 + c], acc);
  out[t*112 + c] = acc;
}

extern "C" void kernel_launch(void* const* d_in, const int* in_sizes, int n_in,
                              void* d_out, int out_size, void* d_ws, size_t ws_size,
                              hipStream_t stream){
  const float* x    = (const float*)d_in[0];
  const int*   ei   = (const int*)d_in[1];
  const int*   batch= (const int*)d_in[2];
  const float* We   = (const float*)d_in[3];
  const float* be   = (const float*)d_in[4];
  const float* Wg   = (const float*)d_in[5];
  const float* a_sg = (const float*)d_in[6];
  const float* a_dg = (const float*)d_in[7];
  const float* bg   = (const float*)d_in[8];
  const float* gam  = (const float*)d_in[9];
  const float* bet  = (const float*)d_in[10];
  const float* W3   = (const float*)d_in[11];
  const float* a_s3 = (const float*)d_in[12];
  const float* a_d3 = (const float*)d_in[13];
  const float* b3   = (const float*)d_in[14];
  const float* gam3 = (const float*)d_in[15];
  const float* bet3 = (const float*)d_in[16];
  const float* M1   = (const float*)d_in[17];
  const float* bm1  = (const float*)d_in[18];
  const float* gm1  = (const float*)d_in[19];
  const float* bb1  = (const float*)d_in[20];
  const float* M2   = (const float*)d_in[21];
  const float* bm2  = (const float*)d_in[22];
  const float* gm2  = (const float*)d_in[23];
  const float* bb2  = (const float*)d_in[24];
  const float* M3   = (const float*)d_in[25];
  const float* bm3  = (const float*)d_in[26];
  float* out = (float*)d_out;

  char* ws = (char*)d_ws;
  size_t off = 0;
  auto alloc = [&](size_t bytes)->char*{
    char* p = ws + off; off += (bytes + 255) & ~(size_t)255; return p;
  };
  float* hA     = (float*)alloc((size_t)N_NODESC*DIM*4);
  unsigned short* hp = (unsigned short*)alloc((size_t)N_NODESC*DIM*2);
  float* al_s   = (float*)alloc((size_t)N_NODESC*8*4);
  float* al_d   = (float*)alloc((size_t)N_NODESC*8*4);
  float* esc    = (float*)alloc((size_t)E_TOT*8*4);
  int* row_ptr  = (int*)alloc((size_t)(N_NODESC+1)*4);
  int* deg      = (int*)alloc((size_t)N_NODESC*4);
  int* cursor   = (int*)alloc((size_t)N_NODESC*4);
  int* scanned  = (int*)alloc((size_t)N_NODESC*4);
  int* bsum     = (int*)alloc((size_t)SCAN_NB*4);
  int* col      = (int*)alloc((size_t)E_TOT*4);
  float* bns4   = (float*)alloc(4*2*DIM*4);   // per-layer BN stats
  float* psum   = (float*)alloc((size_t)NGRAPH*DIM*4);
  int* pcnt     = (int*)alloc(NGRAPH*4);
  float* h1buf  = (float*)alloc((size_t)NGRAPH*72*4);
  float* h2buf  = (float*)alloc((size_t)NGRAPH*36*4);
  (void)ws_size; (void)n_in; (void)in_sizes; (void)out_size;

  const int GEMM_GRID = (N_NODESC + 63)/64;                        // 782
  const size_t GEMM_LDS = (KC*SW_STRIDE + KC*SAT_STRIDE + 2*DIM)*4; // 38592 B

  // CSR build (same graph reused by all 4 GAT layers) — parallel scan
  hipMemsetAsync(deg, 0, (size_t)N_NODESC*4, stream);
  hipMemsetAsync(bns4, 0, 4*2*DIM*4, stream);
  k_count<<<(E_TOT+255)/256, 256, 0, stream>>>(ei, deg);
  k_scan1<<<SCAN_NB, 256, 0, stream>>>(deg, scanned, bsum);
  k_scan2<<<1, 128, 0, stream>>>(bsum);
  k_scan3<<<(N_NODESC+255)/256, 256, 0, stream>>>(scanned, bsum, row_ptr, cursor);
  k_scatter<<<(E_TOT+255)/256, 256, 0, stream>>>(ei, cursor, col);

  // embed: hA = x @ We + be (f32 out)
  k_gemm_fused<<<GEMM_GRID, 256, GEMM_LDS, stream>>>(
      x, We, be, nullptr, nullptr, hA, nullptr, nullptr, nullptr, 128, 0,
      nullptr, nullptr, nullptr);

  for (int L=0; L<4; ++L){
    const float* W  = (L<3) ? (Wg  + (size_t)L*DIM*DIM) : W3;
    const float* as = (L<3) ? (a_sg + (size_t)L*8*18)   : a_s3;
    const float* ad = (L<3) ? (a_dg + (size_t)L*8*18)   : a_d3;
    const float* bb = (L<3) ? (bg  + L*DIM) : b3;
    int H = (L<3) ? 8 : 1;
    int C = (L<3) ? 18 : 144;
    // BN of the PREVIOUS layer's output is applied while staging A
    const float* bnp = (L==0) ? nullptr : bns4 + (size_t)(L-1)*2*DIM;
    const float* gmp = (L==0) ? nullptr : gam + (size_t)(L-1)*DIM;
    const float* btp = (L==0) ? nullptr : bet + (size_t)(L-1)*DIM;
    k_gemm_fused<<<GEMM_GRID, 256, GEMM_LDS, stream>>>(
        hA, W, nullptr, as, ad, nullptr, hp, al_s, al_d, DIM, H, bnp, gmp, btp);
    k_edge_softmax<<<(N_NODESC*H+255)/256, 256, 0, stream>>>(
        al_s, al_d, row_ptr, col, esc, H);
    k_aggregate2<<<(N_NODESC*72+255)/256, 256, 0, stream>>>(
        (const unsigned*)hp, esc, row_ptr, col, bb, hA, H, C/2);
    k_bnstats<<<256, 192, 0, stream>>>(hA, bns4 + (size_t)L*2*DIM);
  }

  hipMemsetAsync(psum, 0, (size_t)NGRAPH*DIM*4, stream);
  k_pool<<<NGRAPH*8, 192, 0, stream>>>(hA, batch, psum, pcnt);
  k_mlp1<<<72, 64, 0, stream>>>(psum, pcnt, bns4 + 3*2*DIM, gam3, bet3,
                                M1, bm1, gm1, bb1, h1buf);
  k_mlp2<<<36, 64, 0, stream>>>(h1buf, M2, bm2, gm2, bb2, h2buf);
  k_mlp3<<<112, 64, 0, stream>>>(h2buf, M3, bm3, out);
}

// Round 9
// 879.172 us; speedup vs baseline: 1.3487x; 1.1274x over previous
//
#include <hip/hip_runtime.h>
#include <cstdint>

#define N_NODESC 50000
#define N_EDGESC 500000
#define E_TOT    550000
#define DIM      144
#define NGRAPH   64
#define EPSV     1e-5f
#define SCAN_NB  ((N_NODESC + 511)/512)

typedef __attribute__((ext_vector_type(8))) short bf16x8;
typedef __attribute__((ext_vector_type(4))) float f32x4;

__device__ __forceinline__ float lrelu(float x){ return x > 0.f ? x : 0.2f*x; }

__device__ __forceinline__ unsigned short f2bf(float f){
  unsigned u = __float_as_uint(f);
  u += 0x7FFF + ((u >> 16) & 1);
  return (unsigned short)(u >> 16);
}
__device__ __forceinline__ float bf2f(unsigned short b){
  return __uint_as_float(((unsigned)b) << 16);
}

// ---------------- CSR build (by dst, self-loops appended) ----------------
__global__ void k_count(const int* __restrict__ ei, int* __restrict__ deg){
  int e = blockIdx.x*blockDim.x + threadIdx.x;
  if (e >= E_TOT) return;
  int d = (e < N_EDGESC) ? ei[N_EDGESC + e] : (e - N_EDGESC);
  atomicAdd(&deg[d], 1);
}

__global__ __launch_bounds__(256) void k_scan1(const int* __restrict__ deg,
    int* __restrict__ scanned, int* __restrict__ bsum){
  __shared__ int ls[256];
  int b = blockIdx.x, t = threadIdx.x;
  int i0 = b*512 + 2*t;
  int e0 = (i0   < N_NODESC) ? deg[i0]   : 0;
  int e1 = (i0+1 < N_NODESC) ? deg[i0+1] : 0;
  int s = e0 + e1;
  ls[t] = s;
  __syncthreads();
  #pragma unroll
  for (int ofs=1; ofs<256; ofs<<=1){
    int v = (t >= ofs) ? ls[t-ofs] : 0;
    __syncthreads();
    ls[t] += v;
    __syncthreads();
  }
  int excl = ls[t] - s;
  if (i0   < N_NODESC) scanned[i0]   = excl;
  if (i0+1 < N_NODESC) scanned[i0+1] = excl + e0;
  if (t == 255) bsum[b] = ls[255];
}

__global__ void k_scan2(int* __restrict__ bsum){
  __shared__ int ls[128];
  int t = threadIdx.x;
  int v = (t < SCAN_NB) ? bsum[t] : 0;
  ls[t] = v;
  __syncthreads();
  #pragma unroll
  for (int ofs=1; ofs<128; ofs<<=1){
    int u = (t >= ofs) ? ls[t-ofs] : 0;
    __syncthreads();
    ls[t] += u;
    __syncthreads();
  }
  if (t < SCAN_NB) bsum[t] = ls[t] - v;
}

__global__ __launch_bounds__(256) void k_scan3(const int* __restrict__ scanned,
    const int* __restrict__ bsum, int* __restrict__ row_ptr, int* __restrict__ cursor){
  int i = blockIdx.x*blockDim.x + threadIdx.x;
  if (i < N_NODESC){
    int v = scanned[i] + bsum[i >> 9];
    row_ptr[i] = v; cursor[i] = v;
  }
  if (i == 0) row_ptr[N_NODESC] = E_TOT;
}

__global__ void k_scatter(const int* __restrict__ ei, int* __restrict__ cursor,
                          int* __restrict__ col){
  int e = blockIdx.x*blockDim.x + threadIdx.x;
  if (e >= E_TOT) return;
  int s, d;
  if (e < N_EDGESC){ s = ei[e]; d = ei[N_EDGESC + e]; } else { s = e - N_EDGESC; d = s; }
  int pos = atomicAdd(&cursor[d], 1);
  col[pos] = s;
}

// ---------------- cast x f32 -> bf16 ----------------
__global__ void k_cast(const float* __restrict__ x, unsigned short* __restrict__ xb){
  int i = blockIdx.x*blockDim.x + threadIdx.x;
  if (i < N_NODESC*128) xb[i] = f2bf(x[i]);
}

// ---------------- weight prep: W'' = diag(sc)*W (+attn-logit cols), bf16, transposed ----------------
// grid = NCOLS blocks (144 or 160); block = 192 threads (thread = k).
// Cols 0..143: W'[k][n] = sc[k]*W[k][n]. Cols 144+c: combined attn weights
// (c<8 -> a_s head c; c>=8 -> a_d head c-8); zero if head >= H.
// bias2[n] = sum_k sh[k]*wcomb[k] (+bias_in[n] for n<144).
__global__ __launch_bounds__(192) void k_prep_w(
    const float* __restrict__ W, const float* __restrict__ bias_in,
    const float* __restrict__ a_s, const float* __restrict__ a_d,
    const float* __restrict__ bnsum, const float* __restrict__ bngam,
    const float* __restrict__ bnbet,
    unsigned short* __restrict__ Wt, float* __restrict__ bias2,
    int K, int SK, int H){
  __shared__ float red[256];
  int np = blockIdx.x, k = threadIdx.x;
  float sc = 1.f, sh = 0.f;
  if (k < K && bnsum){
    float mu  = bnsum[k] * (1.f/N_NODESC);
    float var = bnsum[K+k] * (1.f/N_NODESC) - mu*mu;
    float inv = rsqrtf(var + EPSV);
    sc = inv * bngam[k];
    sh = bnbet[k] - mu*sc;
  }
  float wcomb = 0.f;
  if (k < K){
    if (np < 144) wcomb = W[(size_t)k*144 + np];
    else if (H > 0){
      int c = np - 144;
      bool iss = c < 8;
      int h = iss ? c : c - 8;
      if (h < H){
        const float* av = iss ? a_s : a_d;
        int C = 144 / H;
        for (int j=0;j<C;++j) wcomb += W[(size_t)k*144 + h*C + j] * av[h*C + j];
      }
    }
  }
  if (k < SK) Wt[(size_t)np*SK + k] = f2bf(wcomb*sc);
  red[k] = (k < K) ? sh*wcomb : 0.f;
  if (k < 64) red[k+192] = 0.f;
  __syncthreads();
  #pragma unroll
  for (int s=128; s>0; s>>=1){
    if (k < s) red[k] += red[k+s];
    __syncthreads();
  }
  if (k == 0){
    float b = red[0];
    if (np < 144 && bias_in) b += bias_in[np];
    bias2[np] = b;
  }
}

// ---------------- MFMA GEMM: hp[M,144] (+al cols) = A[M,KA](bf16) @ Wt^T ----------------
// Block 256 = 4 waves; wave computes 16 rows x NT*16 cols. No LDS.
// A-frag: A[m=lane&15][k=quad*8+j]; B-frag: Wt[n=lane&15+16t][k=quad*8+j];
// D: col=lane&15, row=quad*4+reg  [verified C/D mapping].
template<int NT, int KS, int SK>
__global__ __launch_bounds__(256) void k_mfma_gemm(
    const unsigned short* __restrict__ A,
    const unsigned short* __restrict__ Wt,
    const float* __restrict__ bias2,
    unsigned short* __restrict__ hp,
    float* __restrict__ al_s, float* __restrict__ al_d,
    int KA, int H){
  int t = threadIdx.x;
  int wave = t >> 6, lane = t & 63;
  int c = lane & 15, quad = lane >> 4;
  int m_base = blockIdx.x*64 + wave*16;
  int mA = m_base + c; if (mA > N_NODESC-1) mA = N_NODESC-1;
  f32x4 acc[NT];
  #pragma unroll
  for (int i=0;i<NT;++i) acc[i] = (f32x4){0.f,0.f,0.f,0.f};
  const unsigned short* Arow = A + (size_t)mA*KA + quad*8;
  #pragma unroll
  for (int ks=0; ks<KS; ++ks){
    bf16x8 af = *(const bf16x8*)(Arow + ks*32);
    #pragma unroll
    for (int tt=0; tt<NT; ++tt){
      bf16x8 bfr = *(const bf16x8*)(Wt + (size_t)(tt*16 + c)*SK + ks*32 + quad*8);
      acc[tt] = __builtin_amdgcn_mfma_f32_16x16x32_bf16(af, bfr, acc[tt], 0, 0, 0);
    }
  }
  #pragma unroll
  for (int tt=0; tt<NT; ++tt){
    int n = tt*16 + c;
    float b = bias2[n];
    #pragma unroll
    for (int r=0;r<4;++r){
      int m = m_base + quad*4 + r;
      if (m < N_NODESC){
        float v = acc[tt][r] + b;
        if (n < 144){
          hp[(size_t)m*144 + n] = f2bf(v);
        } else {
          int cc = n - 144;
          if (cc < 8){ if (cc < H) al_s[m*H + cc] = v; }
          else { int h = cc - 8; if (h < H) al_d[m*H + h] = v; }
        }
      }
    }
  }
}

// ---------------- segment softmax: one thread per (node, head) ----------------
#define EB 8
__global__ __launch_bounds__(256) void k_edge_softmax(
    const float* __restrict__ al_s, const float* __restrict__ al_d,
    const int* __restrict__ row_ptr, const int* __restrict__ col,
    float* __restrict__ esc, int H){
  int idx = blockIdx.x*blockDim.x + threadIdx.x;
  if (idx >= N_NODESC*H) return;
  int n = idx / H, h = idx - n*H;
  int p0 = row_ptr[n], p1 = row_ptr[n+1];
  float ald = al_d[idx];
  float m = -3.4e38f;
  for (int base = p0; base < p1; base += EB){
    int cnt = min(EB, p1 - base);
    int ss[EB];
    #pragma unroll
    for (int i=0;i<EB;++i) if (i<cnt) ss[i] = col[base+i];
    float sc[EB];
    #pragma unroll
    for (int i=0;i<EB;++i) if (i<cnt) sc[i] = lrelu(al_s[ss[i]*H + h] + ald);
    #pragma unroll
    for (int i=0;i<EB;++i) if (i<cnt){
      esc[(size_t)(base+i)*H + h] = sc[i];
      m = fmaxf(m, sc[i]);
    }
  }
  float den = 0.f;
  for (int e = p0; e < p1; ++e) den += __expf(esc[(size_t)e*H + h] - m);
  float inv = 1.f/(den + 1e-16f);
  for (int e = p0; e < p1; ++e)
    esc[(size_t)e*H + h] = __expf(esc[(size_t)e*H + h] - m) * inv;
}

// ---------------- weighted gather (batched prefetch), bf16 in, bf16 out ----------------
__global__ __launch_bounds__(256) void k_aggregate2(
    const unsigned* __restrict__ hp2, const float* __restrict__ w,
    const int* __restrict__ row_ptr, const int* __restrict__ col,
    const float* __restrict__ bias, unsigned* __restrict__ out,
    int H, int C2){
  int idx = blockIdx.x*blockDim.x + threadIdx.x;
  if (idx >= N_NODESC*72) return;
  int n = idx / 72, cp = idx - n*72;
  int h = cp / C2;
  int p0 = row_ptr[n], p1 = row_ptr[n+1];
  float a0 = 0.f, a1 = 0.f;
  for (int base = p0; base < p1; base += EB){
    int cnt = min(EB, p1 - base);
    int ss[EB]; float ww[EB];
    #pragma unroll
    for (int i=0;i<EB;++i) if (i<cnt){
      ss[i] = col[base+i];
      ww[i] = w[(size_t)(base+i)*H + h];
    }
    unsigned vv[EB];
    #pragma unroll
    for (int i=0;i<EB;++i) if (i<cnt) vv[i] = hp2[(size_t)ss[i]*72 + cp];
    #pragma unroll
    for (int i=0;i<EB;++i) if (i<cnt){
      a0 = fmaf(ww[i], __uint_as_float(vv[i] << 16), a0);
      a1 = fmaf(ww[i], __uint_as_float(vv[i] & 0xFFFF0000u), a1);
    }
  }
  int c0 = 2*cp;
  float r0 = fmaxf(a0 + bias[c0],   0.f);
  float r1 = fmaxf(a1 + bias[c0+1], 0.f);
  out[(size_t)n*72 + cp] = (unsigned)f2bf(r0) | ((unsigned)f2bf(r1) << 16);
}

// ---------------- batchnorm stats over bf16 hA ----------------
__global__ __launch_bounds__(128) void k_bnstats(const unsigned* __restrict__ h2,
                                                 float* __restrict__ sums){
  int t = threadIdx.x;
  if (t >= 72) return;
  int rows = (N_NODESC + gridDim.x - 1)/gridDim.x;
  int n0 = blockIdx.x*rows, n1 = min(N_NODESC, n0+rows);
  float s0=0.f,q0=0.f,s1=0.f,q1=0.f;
  for (int n = n0; n < n1; ++n){
    unsigned v = h2[(size_t)n*72 + t];
    float f0 = __uint_as_float(v << 16);
    float f1 = __uint_as_float(v & 0xFFFF0000u);
    s0 += f0; q0 += f0*f0; s1 += f1; q1 += f1*f1;
  }
  atomicAdd(&sums[2*t],       s0);
  atomicAdd(&sums[2*t+1],     s1);
  atomicAdd(&sums[144+2*t],   q0);
  atomicAdd(&sums[144+2*t+1], q1);
}

// ---------------- per-graph mean pool over bf16 hA ----------------
__device__ int lbound(const int* a, int n, int v){
  int lo = 0, hi = n;
  while (lo < hi){ int m = (lo+hi) >> 1; if (a[m] < v) lo = m+1; else hi = m; }
  return lo;
}

__global__ __launch_bounds__(128) void k_pool(const unsigned* __restrict__ h2,
    const int* __restrict__ batch, float* __restrict__ sums, int* __restrict__ cnts){
  int g = blockIdx.x & 63, part = blockIdx.x >> 6;
  __shared__ int sb[2];
  if (threadIdx.x == 0){ sb[0] = lbound(batch, N_NODESC, g); sb[1] = lbound(batch, N_NODESC, g+1); }
  __syncthreads();
  int lo = sb[0], hi = sb[1];
  int t = threadIdx.x;
  if (t < 72){
    float a0 = 0.f, a1 = 0.f;
    for (int n = lo + part; n < hi; n += 8){
      unsigned v = h2[(size_t)n*72 + t];
      a0 += __uint_as_float(v << 16);
      a1 += __uint_as_float(v & 0xFFFF0000u);
    }
    atomicAdd(&sums[g*DIM + 2*t],   a0);
    atomicAdd(&sums[g*DIM + 2*t+1], a1);
  }
  if (t == 0 && part == 0) cnts[g] = hi - lo;
}

// ---------------- MLP head: column-parallel, BN via wave reduction ----------------
__global__ __launch_bounds__(64) void k_mlp1(const float* __restrict__ psum,
    const int* __restrict__ cnts,
    const float* __restrict__ bn3, const float* __restrict__ gam3,
    const float* __restrict__ bet3,
    const float* __restrict__ M1, const float* __restrict__ bm1,
    const float* __restrict__ gm1, const float* __restrict__ bb1,
    float* __restrict__ h1){
  __shared__ float sSc[144], sSh[144];
  int t = threadIdx.x, c = blockIdx.x;
  for (int i=t; i<144; i+=64){
    float mu  = bn3[i] * (1.f/N_NODESC);
    float var = bn3[144+i] * (1.f/N_NODESC) - mu*mu;
    float sc  = rsqrtf(var + EPSV) * gam3[i];
    sSc[i] = sc; sSh[i] = bet3[i] - mu*sc;
  }
  __syncthreads();
  float invc = 1.f / (float)max(cnts[t], 1);
  float acc = bm1[c];
  const float* pr = psum + t*144;
  for (int k=0; k<144; ++k){
    float g = fmaf(pr[k]*invc, sSc[k], sSh[k]);
    acc = fmaf(g, M1[k*72 + c], acc);
  }
  float s = acc, q = acc*acc;
  #pragma unroll
  for (int o=32; o>0; o>>=1){ s += __shfl_xor(s, o, 64); q += __shfl_xor(q, o, 64); }
  float mu = s*(1.f/64.f), var = q*(1.f/64.f) - mu*mu;
  float v = (acc - mu)*rsqrtf(var + EPSV)*gm1[c] + bb1[c];
  h1[t*72 + c] = fmaxf(v, 0.f);
}

__global__ __launch_bounds__(64) void k_mlp2(const float* __restrict__ h1,
    const float* __restrict__ M2, const float* __restrict__ bm2,
    const float* __restrict__ gm2, const float* __restrict__ bb2,
    float* __restrict__ h2){
  int t = threadIdx.x, c = blockIdx.x;
  float acc = bm2[c];
  const float* pr = h1 + t*72;
  for (int k=0; k<72; ++k) acc = fmaf(pr[k], M2[k*36 + c], acc);
  float s = acc, q = acc*acc;
  #pragma unroll
  for (int o=32; o>0; o>>=1){ s += __shfl_xor(s, o, 64); q += __shfl_xor(q, o, 64); }
  float mu = s*(1.f/64.f), var = q*(1.f/64.f) - mu*mu;
  float v = (acc - mu)*rsqrtf(var + EPSV)*gm2[c] + bb2[c];
  h2[t*36 + c] = fmaxf(v, 0.f);
}

__global__ __launch_bounds__(64) void k_mlp3(const float* __restrict__ h2,
    const float* __restrict__ M3, const float* __restrict__ bm3,
    float* __restrict__ out){
  int t = threadIdx.x, c = blockIdx.x;
  float acc = bm3[c];
  const float* pr = h2 + t*36;
  for (int k=0; k<36; ++k) acc = fmaf(pr[k], M3[k*112 + c], acc);
  out[t*112 + c] = acc;
}

extern "C" void kernel_launch(void* const* d_in, const int* in_sizes, int n_in,
                              void* d_out, int out_size, void* d_ws, size_t ws_size,
                              hipStream_t stream){
  const float* x    = (const float*)d_in[0];
  const int*   ei   = (const int*)d_in[1];
  const int*   batch= (const int*)d_in[2];
  const float* We   = (const float*)d_in[3];
  const float* be   = (const float*)d_in[4];
  const float* Wg   = (const float*)d_in[5];
  const float* a_sg = (const float*)d_in[6];
  const float* a_dg = (const float*)d_in[7];
  const float* bg   = (const float*)d_in[8];
  const float* gam  = (const float*)d_in[9];
  const float* bet  = (const float*)d_in[10];
  const float* W3   = (const float*)d_in[11];
  const float* a_s3 = (const float*)d_in[12];
  const float* a_d3 = (const float*)d_in[13];
  const float* b3   = (const float*)d_in[14];
  const float* gam3 = (const float*)d_in[15];
  const float* bet3 = (const float*)d_in[16];
  const float* M1   = (const float*)d_in[17];
  const float* bm1  = (const float*)d_in[18];
  const float* gm1  = (const float*)d_in[19];
  const float* bb1  = (const float*)d_in[20];
  const float* M2   = (const float*)d_in[21];
  const float* bm2  = (const float*)d_in[22];
  const float* gm2  = (const float*)d_in[23];
  const float* bb2  = (const float*)d_in[24];
  const float* M3   = (const float*)d_in[25];
  const float* bm3  = (const float*)d_in[26];
  float* out = (float*)d_out;

  char* ws = (char*)d_ws;
  size_t off = 0;
  auto alloc = [&](size_t bytes)->char*{
    char* p = ws + off; off += (bytes + 255) & ~(size_t)255; return p;
  };
  unsigned short* hAb = (unsigned short*)alloc((size_t)N_NODESC*DIM*2);
  unsigned short* hp  = (unsigned short*)alloc((size_t)N_NODESC*DIM*2);
  unsigned short* xb  = (unsigned short*)alloc((size_t)N_NODESC*128*2);
  float* al_s   = (float*)alloc((size_t)N_NODESC*8*4);
  float* al_d   = (float*)alloc((size_t)N_NODESC*8*4);
  float* esc    = (float*)alloc((size_t)E_TOT*8*4);
  int* row_ptr  = (int*)alloc((size_t)(N_NODESC+1)*4);
  int* deg      = (int*)alloc((size_t)N_NODESC*4);
  int* cursor   = (int*)alloc((size_t)N_NODESC*4);
  int* scanned  = (int*)alloc((size_t)N_NODESC*4);
  int* bsum     = (int*)alloc((size_t)SCAN_NB*4);
  int* col      = (int*)alloc((size_t)E_TOT*4);
  float* bns4   = (float*)alloc(4*2*DIM*4);
  float* psum   = (float*)alloc((size_t)NGRAPH*DIM*4);
  int* pcnt     = (int*)alloc(NGRAPH*4);
  float* h1buf  = (float*)alloc((size_t)NGRAPH*72*4);
  float* h2buf  = (float*)alloc((size_t)NGRAPH*36*4);
  unsigned short* Wt = (unsigned short*)alloc((size_t)160*168*2);
  float* bias2  = (float*)alloc(160*4);
  (void)ws_size; (void)n_in; (void)in_sizes; (void)out_size;

  const int GEMM_GRID = (N_NODESC + 63)/64;   // 782

  // CSR build
  hipMemsetAsync(deg, 0, (size_t)N_NODESC*4, stream);
  hipMemsetAsync(bns4, 0, 4*2*DIM*4, stream);
  k_count<<<(E_TOT+255)/256, 256, 0, stream>>>(ei, deg);
  k_scan1<<<SCAN_NB, 256, 0, stream>>>(deg, scanned, bsum);
  k_scan2<<<1, 128, 0, stream>>>(bsum);
  k_scan3<<<(N_NODESC+255)/256, 256, 0, stream>>>(scanned, bsum, row_ptr, cursor);
  k_scatter<<<(E_TOT+255)/256, 256, 0, stream>>>(ei, cursor, col);

  // embed: hAb = bf16(x) @ We + be  (MFMA, K=128, N=144, no attn cols)
  k_cast<<<(N_NODESC*128+255)/256, 256, 0, stream>>>(x, xb);
  k_prep_w<<<144, 192, 0, stream>>>(We, be, nullptr, nullptr,
                                    nullptr, nullptr, nullptr, Wt, bias2, 128, 136, 0);
  k_mfma_gemm<9,4,136><<<GEMM_GRID, 256, 0, stream>>>(
      xb, Wt, bias2, hAb, nullptr, nullptr, 128, 0);

  for (int L=0; L<4; ++L){
    const float* W  = (L<3) ? (Wg  + (size_t)L*DIM*DIM) : W3;
    const float* as = (L<3) ? (a_sg + (size_t)L*8*18)   : a_s3;
    const float* ad = (L<3) ? (a_dg + (size_t)L*8*18)   : a_d3;
    const float* bb = (L<3) ? (bg  + L*DIM) : b3;
    int H = (L<3) ? 8 : 1;
    int C = (L<3) ? 18 : 144;
    const float* bnp = (L==0) ? nullptr : bns4 + (size_t)(L-1)*2*DIM;
    const float* gmp = (L==0) ? nullptr : gam + (size_t)(L-1)*DIM;
    const float* btp = (L==0) ? nullptr : bet + (size_t)(L-1)*DIM;
    // BN folded into weights; attn logits folded as 16 extra output columns
    k_prep_w<<<160, 192, 0, stream>>>(W, nullptr, as, ad,
                                      bnp, gmp, btp, Wt, bias2, 144, 168, H);
    k_mfma_gemm<10,5,168><<<GEMM_GRID, 256, 0, stream>>>(
        hAb, Wt, bias2, hp, al_s, al_d, 144, H);
    k_edge_softmax<<<(N_NODESC*H+255)/256, 256, 0, stream>>>(
        al_s, al_d, row_ptr, col, esc, H);
    k_aggregate2<<<(N_NODESC*72+255)/256, 256, 0, stream>>>(
        (const unsigned*)hp, esc, row_ptr, col, bb, (unsigned*)hAb, H, C/2);
    k_bnstats<<<256, 128, 0, stream>>>((const unsigned*)hAb, bns4 + (size_t)L*2*DIM);
  }

  hipMemsetAsync(psum, 0, (size_t)NGRAPH*DIM*4, stream);
  k_pool<<<NGRAPH*8, 128, 0, stream>>>((const unsigned*)hAb, batch, psum, pcnt);
  k_mlp1<<<72, 64, 0, stream>>>(psum, pcnt, bns4 + 3*2*DIM, gam3, bet3,
                                M1, bm1, gm1, bb1, h1buf);
  k_mlp2<<<36, 64, 0, stream>>>(h1buf, M2, bm2, gm2, bb2, h2buf);
  k_mlp3<<<112, 64, 0, stream>>>(h2buf, M3, bm3, out);
}